// Round 2
// baseline (695.721 us; speedup 1.0000x reference)
//
#include <hip/hip_runtime.h>
#include <cstdint>
#include <cstddef>

#define BB 64
#define HH 168
#define NN 512
#define FF 8
#define UL 128   // lstm units
#define GD 512   // gate dim (4*UL)

__device__ __forceinline__ float sigf(float x){ return 1.0f/(1.0f+__expf(-x)); }
__device__ __forceinline__ float tanhfast(float x){ return 1.0f - 2.0f/(1.0f+__expf(2.0f*x)); }
__device__ __forceinline__ float rdlane(float v, int l){
  return __uint_as_float(__builtin_amdgcn_readlane(__float_as_uint(v), l));
}
// fmac with guaranteed SGPR broadcast operand: acc += s*w
#define SFMAC(acc, s, w) asm("v_fmac_f32 %0, %1, %2" : "+v"(acc) : "s"(s), "v"(w))

// ---------------- summaries: partial sums over half the H axis ----------------
__global__ __launch_bounds__(256) void k_sum(const float* __restrict__ in, float* __restrict__ ps){
  int bid = blockIdx.x;
  int b = bid>>2, nh = (bid>>1)&1, hh = bid&1;
  int n = nh*256 + threadIdx.x;
  int h0 = hh*84;
  const float* p = in + ((size_t)(b*HH + h0)*NN + n)*FF;
  float s1=0.f,s2=0.f,s3=0.f,s4=0.f,st=0.f;
  #pragma unroll 4
  for(int h=0;h<84;++h){
    float x = p[(size_t)h*NN*FF];
    float hc = (float)(h+h0) - 83.5f;
    s1 += x;
    float x2 = x*x;
    s2 += x2;
    s3 += x2*x;
    s4 += x2*x2;
    st += hc*x;
  }
  float* o = ps + ((size_t)((b*NN+n)*2 + hh))*8;
  o[0]=s1; o[1]=s2; o[2]=s3; o[3]=s4; o[4]=st;
}

__global__ __launch_bounds__(256) void k_sumc(const float* __restrict__ ps, float* __restrict__ nf){
  int idx = blockIdx.x*256 + threadIdx.x;
  const float* a = ps + (size_t)idx*16;
  const float* c2 = a + 8;
  float s1 = a[0]+c2[0], s2 = a[1]+c2[1], s3 = a[2]+c2[2], s4 = a[3]+c2[3], st = a[4]+c2[4];
  float s1h = c2[0], s2h = c2[1];
  const float iH = 1.0f/168.0f, iHh = 1.0f/84.0f;
  float mean = s1*iH, meanh = s1h*iHh;
  float ex2 = s2*iH, ex3 = s3*iH, ex4 = s4*iH;
  float m2 = ex2 - mean*mean;
  float m3 = ex3 - 3.0f*mean*ex2 + 2.0f*mean*mean*mean;
  float m4 = ex4 - 4.0f*mean*ex3 + 6.0f*mean*mean*ex2 - 3.0f*mean*mean*mean*mean;
  m2 = fmaxf(m2, 0.0f);
  float stdf = sqrtf(m2);
  float m2h = fmaxf(s2h*iHh - meanh*meanh, 0.0f);
  float stdh = sqrtf(m2h);
  float denom = m2*stdf;
  float skew = denom > 0.0f ? m3/denom : 0.0f;
  float kurt = m2 > 0.0f ? (m4/(m2*m2) - 3.0f) : 0.0f;
  float slope = st * (1.0f/395122.0f);
  float* o = nf + (size_t)idx*7;
  o[0]=mean; o[1]=meanh; o[2]=stdf; o[3]=stdh; o[4]=skew; o[5]=kurt; o[6]=slope;
}

// ---------------- GCN layer 1 ----------------
__global__ __launch_bounds__(256) void k_gcn1(const float* __restrict__ nf, const float* __restrict__ adj,
        const float* __restrict__ w1, const float* __restrict__ b1, float* __restrict__ h1){
  __shared__ float t_s[NN*32];
  __shared__ float adj_s[128*68];
  int b = blockIdx.x>>2, n0 = (blockIdx.x&3)*128;
  int tid = threadIdx.x;
  {
    int c = tid&31;
    float w1c[7];
    #pragma unroll
    for(int k=0;k<7;++k) w1c[k] = w1[k*32+c];
    for(int idx=tid; idx<NN*32; idx+=256){
      int m = idx>>5;
      const float* nfp = nf + (size_t)(b*NN+m)*7;
      float acc = 0.f;
      #pragma unroll
      for(int k=0;k<7;++k) acc += nfp[k]*w1c[k];
      t_s[idx] = acc;
    }
  }
  int c2 = tid&15, nl = tid>>4;
  float acc[8][2];
  #pragma unroll
  for(int j=0;j<8;++j){acc[j][0]=0.f;acc[j][1]=0.f;}
  for(int mt=0; mt<8; ++mt){
    __syncthreads();
    for(int idx=tid; idx<128*64; idx+=256){
      int r = idx>>6, cc = idx&63;
      adj_s[r*68+cc] = adj[(size_t)(n0+r)*NN + mt*64 + cc];
    }
    __syncthreads();
    for(int mm=0; mm<64; mm+=4){
      float2 tv[4];
      #pragma unroll
      for(int q=0;q<4;++q) tv[q] = *(const float2*)&t_s[(mt*64+mm+q)*32 + 2*c2];
      #pragma unroll
      for(int j=0;j<8;++j){
        float4 a4 = *(const float4*)&adj_s[(nl+16*j)*68 + mm];
        acc[j][0] += a4.x*tv[0].x + a4.y*tv[1].x + a4.z*tv[2].x + a4.w*tv[3].x;
        acc[j][1] += a4.x*tv[0].y + a4.y*tv[1].y + a4.z*tv[2].y + a4.w*tv[3].y;
      }
    }
  }
  float bb0 = b1[2*c2], bb1 = b1[2*c2+1];
  #pragma unroll
  for(int j=0;j<8;++j){
    int n = n0 + nl + 16*j;
    float2 v;
    v.x = fmaxf(acc[j][0]+bb0, 0.0f);
    v.y = fmaxf(acc[j][1]+bb1, 0.0f);
    *(float2*)&h1[(size_t)(b*NN+n)*32 + 2*c2] = v;
  }
}

// ---------------- GCN layer 2 ----------------
__global__ __launch_bounds__(256) void k_gcn2(const float* __restrict__ h1, const float* __restrict__ adj,
        const float* __restrict__ w2, const float* __restrict__ b2, float* __restrict__ g){
  __shared__ float t_s[NN*16];
  __shared__ float adj_s[128*68];
  int b = blockIdx.x>>2, n0 = (blockIdx.x&3)*128;
  int tid = threadIdx.x;
  {
    int jh = tid&7;
    float w2c0[32], w2c1[32];
    #pragma unroll
    for(int c=0;c<32;++c){ w2c0[c] = w2[c*16+2*jh]; w2c1[c] = w2[c*16+2*jh+1]; }
    for(int idx=tid; idx<NN*8; idx+=256){
      int m = idx>>3;
      const float4* hp = (const float4*)(h1 + (size_t)(b*NN+m)*32);
      float a0=0.f, a1=0.f;
      #pragma unroll
      for(int q=0;q<8;++q){
        float4 hv = hp[q];
        a0 += hv.x*w2c0[4*q] + hv.y*w2c0[4*q+1] + hv.z*w2c0[4*q+2] + hv.w*w2c0[4*q+3];
        a1 += hv.x*w2c1[4*q] + hv.y*w2c1[4*q+1] + hv.z*w2c1[4*q+2] + hv.w*w2c1[4*q+3];
      }
      t_s[m*16+2*jh] = a0;
      t_s[m*16+2*jh+1] = a1;
    }
  }
  int j = tid&15, nl = tid>>4;
  float acc[8];
  #pragma unroll
  for(int q=0;q<8;++q) acc[q]=0.f;
  for(int mt=0; mt<8; ++mt){
    __syncthreads();
    for(int idx=tid; idx<128*64; idx+=256){
      int r = idx>>6, cc = idx&63;
      adj_s[r*68+cc] = adj[(size_t)(n0+r)*NN + mt*64 + cc];
    }
    __syncthreads();
    for(int mm=0; mm<64; mm+=4){
      float tv[4];
      #pragma unroll
      for(int q=0;q<4;++q) tv[q] = t_s[(mt*64+mm+q)*16 + j];
      #pragma unroll
      for(int q=0;q<8;++q){
        float4 a4 = *(const float4*)&adj_s[(nl+16*q)*68 + mm];
        acc[q] += a4.x*tv[0] + a4.y*tv[1] + a4.z*tv[2] + a4.w*tv[3];
      }
    }
  }
  float bbj = b2[j];
  #pragma unroll
  for(int q=0;q<8;++q){
    int n = n0 + nl + 16*q;
    g[(size_t)(b*NN+n)*16 + j] = fmaxf(acc[q]+bbj, 0.0f);
  }
}

// ---------------- conv1 -> pool -> conv2 (256 threads, c-split partials) ----------------
__global__ __launch_bounds__(256) void k_conv(const float* __restrict__ g, const float* __restrict__ wc1,
        const float* __restrict__ bc1, const float* __restrict__ wc2, const float* __restrict__ bc2,
        float* __restrict__ feat){
  __shared__ float g_s[NN*16];      // 32KB
  __shared__ float w1_s[3*NN*4];    // 24KB
  __shared__ float c1p[4][4][16];
  __shared__ float c1_s[4][16];
  __shared__ float p_s[4][8];
  int b = blockIdx.x, tid = threadIdx.x;
  for(int idx=tid; idx<NN*16; idx+=256) g_s[idx] = g[(size_t)b*NN*16 + idx];
  for(int idx=tid; idx<3*NN*4; idx+=256) w1_s[idx] = wc1[idx];
  __syncthreads();
  {
    int q = tid>>6, p = tid&63, o = p>>4, x = p&15;
    int c0 = q*128;
    float acc = 0.f;
    #pragma unroll
    for(int k=0;k<3;++k){
      int xx = x + k - 1;
      if(xx>=0 && xx<16){
        #pragma unroll 4
        for(int c=c0;c<c0+128;++c) acc += g_s[c*16+xx]*w1_s[(k*NN+c)*4+o];
      }
    }
    c1p[q][o][x] = acc;
  }
  __syncthreads();
  if(tid<64){
    int o = tid>>4, x = tid&15;
    c1_s[o][x] = c1p[0][o][x]+c1p[1][o][x]+c1p[2][o][x]+c1p[3][o][x] + bc1[o];
  }
  __syncthreads();
  if(tid<32){
    int oo = tid>>3, xp = tid&7;
    float pv = 0.5f*(c1_s[oo][2*xp]+c1_s[oo][2*xp+1]);
    p_s[oo][xp] = pv;
    feat[b*192 + 32 + oo*8 + xp] = pv;
  }
  __syncthreads();
  if(tid<32){
    int oo = tid>>3, x2 = tid&7;
    float a2 = bc2[oo];
    #pragma unroll
    for(int k=0;k<3;++k){
      int xx = x2 + k - 1;
      if(xx>=0 && xx<8){
        #pragma unroll
        for(int c=0;c<4;++c) a2 += p_s[c][xx]*wc2[(k*4+c)*4+oo];
      }
    }
    feat[b*192 + oo*8 + x2] = a2;
  }
}

// ---------------- LSTM1 recurrence: 256 threads, 2 gate-cols/thread, readlane broadcast ----------------
// thread tid owns cols tid (i/f) and tid+256 (g/o). Weights in registers (~300 VGPR, 1 wave/SIMD).
__global__ __launch_bounds__(256,1) void k_lstm1(const float* __restrict__ in, const float* __restrict__ k1,
        const float* __restrict__ rk1, const float* __restrict__ b1, float* __restrict__ l1){
  __shared__ float seq_s[HH*FF];
  __shared__ float h_s[UL];
  __shared__ float a_s[GD];
  int b = blockIdx.x, tid = threadIdx.x;
  int lane = tid & 63;
  float wrA[UL], wrB[UL], wkA[FF], wkB[FF];
  #pragma unroll
  for(int j=0;j<UL;++j){ wrA[j] = rk1[j*GD+tid]; wrB[j] = rk1[j*GD+tid+256]; }
  #pragma unroll
  for(int f=0;f<FF;++f){ wkA[f] = k1[f*GD+tid]; wkB[f] = k1[f*GD+tid+256]; }
  float bzA = b1[tid], bzB = b1[tid+256];
  for(int idx=tid; idx<HH*FF; idx+=256)
    seq_s[idx] = in[(size_t)(b*HH + (idx>>3))*NN*FF + (idx&7)];
  if(tid<UL) h_s[tid]=0.0f;
  float c = 0.0f;
  __syncthreads();
  #pragma unroll 1
  for(int t=0;t<HH;++t){
    // input projection (x broadcast from LDS)
    float4 x0 = *(const float4*)&seq_s[t*FF];
    float4 x1 = *(const float4*)&seq_s[t*FF+4];
    float zA = bzA + x0.x*wkA[0]+x0.y*wkA[1]+x0.z*wkA[2]+x0.w*wkA[3]
                   + x1.x*wkA[4]+x1.y*wkA[5]+x1.z*wkA[6]+x1.w*wkA[7];
    float zB = bzB + x0.x*wkB[0]+x0.y*wkB[1]+x0.z*wkB[2]+x0.w*wkB[3]
                   + x1.x*wkB[4]+x1.y*wkB[5]+x1.z*wkB[6]+x1.w*wkB[7];
    // recurrent dot: h via one b64/lane + in-register broadcast
    float2 hv = *(const float2*)&h_s[2*lane];
    float a0=0.f,a1=0.f,bb0=0.f,bb1=0.f;
    #pragma unroll
    for(int l=0;l<64;++l){
      float se = rdlane(hv.x, l);   // h[2l]
      float so = rdlane(hv.y, l);   // h[2l+1]
      SFMAC(a0, se, wrA[2*l]);
      SFMAC(a1, so, wrA[2*l+1]);
      SFMAC(bb0, se, wrB[2*l]);
      SFMAC(bb1, so, wrB[2*l+1]);
    }
    float zz0 = zA + (a0+a1);
    float zz1 = zB + (bb0+bb1);
    float actA = sigf(zz0);                              // i or f gate
    float actB = (tid<UL) ? tanhfast(zz1) : sigf(zz1);   // g or o gate
    a_s[tid] = actA;
    a_s[256+tid] = actB;
    __syncthreads();
    if(tid<UL){
      float ia=a_s[tid], fa=a_s[UL+tid], ga=a_s[2*UL+tid], oa=a_s[3*UL+tid];
      c = fa*c + ia*ga;
      float hn = oa*tanhfast(c);
      h_s[tid] = hn;
      l1[((size_t)b*HH + t)*UL + tid] = hn;
    }
    __syncthreads();
  }
}

// ---------------- zin2 = l1 @ k2 + b2 ----------------
__global__ __launch_bounds__(256) void k_zin2(const float* __restrict__ l1, const float* __restrict__ k2,
        const float* __restrict__ b2, float* __restrict__ zin){
  __shared__ float l_s[21*UL];
  int b = blockIdx.x>>3, t0 = (blockIdx.x&7)*21;
  int tid = threadIdx.x;
  for(int idx=tid; idx<21*UL; idx+=256)
    l_s[idx] = l1[((size_t)b*HH + t0 + (idx>>7))*UL + (idx&127)];
  __syncthreads();
  float acc0[21], acc1[21];
  #pragma unroll
  for(int q=0;q<21;++q){acc0[q]=0.f;acc1[q]=0.f;}
  for(int j=0;j<UL;j+=4){
    float kv00=k2[j*GD+tid],     kv01=k2[(j+1)*GD+tid],     kv02=k2[(j+2)*GD+tid],     kv03=k2[(j+3)*GD+tid];
    float kv10=k2[j*GD+tid+256], kv11=k2[(j+1)*GD+tid+256], kv12=k2[(j+2)*GD+tid+256], kv13=k2[(j+3)*GD+tid+256];
    #pragma unroll
    for(int q=0;q<21;++q){
      float4 lv = *(const float4*)&l_s[q*UL + j];
      acc0[q] += lv.x*kv00 + lv.y*kv01 + lv.z*kv02 + lv.w*kv03;
      acc1[q] += lv.x*kv10 + lv.y*kv11 + lv.z*kv12 + lv.w*kv13;
    }
  }
  float bb0 = b2[tid], bb1 = b2[tid+256];
  #pragma unroll
  for(int q=0;q<21;++q){
    zin[((size_t)b*HH + t0 + q)*GD + tid]       = acc0[q] + bb0;
    zin[((size_t)b*HH + t0 + q)*GD + tid + 256] = acc1[q] + bb1;
  }
}

// ---------------- LSTM2 recurrence (same structure, z from prefetched zin) ----------------
__global__ __launch_bounds__(256,1) void k_lstm2(const float* __restrict__ zin, const float* __restrict__ rk2,
        float* __restrict__ feat){
  __shared__ float h_s[UL];
  __shared__ float a_s[GD];
  int b = blockIdx.x, tid = threadIdx.x;
  int lane = tid & 63;
  float wrA[UL], wrB[UL];
  #pragma unroll
  for(int j=0;j<UL;++j){ wrA[j] = rk2[j*GD+tid]; wrB[j] = rk2[j*GD+tid+256]; }
  if(tid<UL) h_s[tid]=0.0f;
  float c = 0.0f;
  float zA = zin[((size_t)b*HH)*GD + tid];
  float zB = zin[((size_t)b*HH)*GD + tid + 256];
  __syncthreads();
  #pragma unroll 1
  for(int t=0;t<HH;++t){
    float nzA = 0.f, nzB = 0.f;
    if(t+1<HH){
      nzA = zin[((size_t)b*HH+t+1)*GD + tid];       // prefetch next step
      nzB = zin[((size_t)b*HH+t+1)*GD + tid + 256];
    }
    float2 hv = *(const float2*)&h_s[2*lane];
    float a0=0.f,a1=0.f,bb0=0.f,bb1=0.f;
    #pragma unroll
    for(int l=0;l<64;++l){
      float se = rdlane(hv.x, l);
      float so = rdlane(hv.y, l);
      SFMAC(a0, se, wrA[2*l]);
      SFMAC(a1, so, wrA[2*l+1]);
      SFMAC(bb0, se, wrB[2*l]);
      SFMAC(bb1, so, wrB[2*l+1]);
    }
    float zz0 = zA + (a0+a1);
    float zz1 = zB + (bb0+bb1);
    float actA = sigf(zz0);
    float actB = (tid<UL) ? tanhfast(zz1) : sigf(zz1);
    a_s[tid] = actA;
    a_s[256+tid] = actB;
    __syncthreads();
    if(tid<UL){
      float ia=a_s[tid], fa=a_s[UL+tid], ga=a_s[2*UL+tid], oa=a_s[3*UL+tid];
      c = fa*c + ia*ga;
      float hn = oa*tanhfast(c);
      h_s[tid] = hn;
      if(t==HH-1) feat[b*192 + 64 + tid] = hn;
    }
    __syncthreads();
    zA = nzA; zB = nzB;
  }
}

// ---------------- final dense ----------------
__global__ __launch_bounds__(256) void k_out(const float* __restrict__ feat, const float* __restrict__ wo,
        const float* __restrict__ bo, float* __restrict__ out){
  int idx = blockIdx.x*256 + threadIdx.x;
  if(idx >= BB*24) return;
  int b = idx/24, p = idx - b*24;
  float a0 = bo[p], a1 = 0.f, a2 = 0.f, a3 = 0.f;
  const float* f = feat + b*192;
  for(int k=0;k<192;k+=4){
    a0 += f[k]*wo[k*24+p];
    a1 += f[k+1]*wo[(k+1)*24+p];
    a2 += f[k+2]*wo[(k+2)*24+p];
    a3 += f[k+3]*wo[(k+3)*24+p];
  }
  out[idx] = (a0+a1)+(a2+a3);
}

extern "C" void kernel_launch(void* const* d_in, const int* in_sizes, int n_in,
                              void* d_out, int out_size, void* d_ws, size_t ws_size,
                              hipStream_t stream){
  const float* inp = (const float*)d_in[0];
  const float* adj = (const float*)d_in[1];
  const float* w1  = (const float*)d_in[2];
  const float* b1  = (const float*)d_in[3];
  const float* w2  = (const float*)d_in[4];
  const float* b2  = (const float*)d_in[5];
  const float* wc1 = (const float*)d_in[6];
  const float* bc1 = (const float*)d_in[7];
  const float* wc2 = (const float*)d_in[8];
  const float* bc2 = (const float*)d_in[9];
  const float* k1  = (const float*)d_in[10];
  const float* rk1 = (const float*)d_in[11];
  const float* bl1 = (const float*)d_in[12];
  const float* k2  = (const float*)d_in[13];
  const float* rk2 = (const float*)d_in[14];
  const float* bl2 = (const float*)d_in[15];
  const float* wo  = (const float*)d_in[16];
  const float* bo  = (const float*)d_in[17];
  float* out = (float*)d_out;
  float* ws = (float*)d_ws;

  float* ps   = ws;
  float* nf   = ps + 524288;
  float* h1   = nf + 229376;
  float* g    = h1 + 1048576;
  float* feat = g  + 524288;
  float* l1   = feat + 12288;
  float* zin  = l1 + 1376256;

  k_sum  <<<dim3(256), dim3(256), 0, stream>>>(inp, ps);
  k_sumc <<<dim3(128), dim3(256), 0, stream>>>(ps, nf);
  k_gcn1 <<<dim3(256), dim3(256), 0, stream>>>(nf, adj, w1, b1, h1);
  k_gcn2 <<<dim3(256), dim3(256), 0, stream>>>(h1, adj, w2, b2, g);
  k_conv <<<dim3(64),  dim3(256), 0, stream>>>(g, wc1, bc1, wc2, bc2, feat);
  k_lstm1<<<dim3(64),  dim3(256), 0, stream>>>(inp, k1, rk1, bl1, l1);
  k_zin2 <<<dim3(512), dim3(256), 0, stream>>>(l1, k2, bl2, zin);
  k_lstm2<<<dim3(64),  dim3(256), 0, stream>>>(zin, rk2, feat);
  k_out  <<<dim3(6),   dim3(256), 0, stream>>>(feat, wo, bo, out);
}

// Round 3
// 433.501 us; speedup vs baseline: 1.6049x; 1.6049x over previous
//
#include <hip/hip_runtime.h>
#include <cstdint>
#include <cstddef>

#define BB 64
#define HH 168
#define NN 512
#define FF 8
#define UL 128   // lstm units
#define GD 512   // gate dim (4*UL)

__device__ __forceinline__ float sigf(float x){ return 1.0f/(1.0f+__expf(-x)); }
__device__ __forceinline__ float tanhfast(float x){ return 1.0f - 2.0f/(1.0f+__expf(2.0f*x)); }

// ---------------- summaries: partial sums over half the H axis ----------------
__global__ __launch_bounds__(256) void k_sum(const float* __restrict__ in, float* __restrict__ ps){
  int bid = blockIdx.x;
  int b = bid>>2, nh = (bid>>1)&1, hh = bid&1;
  int n = nh*256 + threadIdx.x;
  int h0 = hh*84;
  const float* p = in + ((size_t)(b*HH + h0)*NN + n)*FF;
  float s1=0.f,s2=0.f,s3=0.f,s4=0.f,st=0.f;
  #pragma unroll 4
  for(int h=0;h<84;++h){
    float x = p[(size_t)h*NN*FF];
    float hc = (float)(h+h0) - 83.5f;
    s1 += x;
    float x2 = x*x;
    s2 += x2;
    s3 += x2*x;
    s4 += x2*x2;
    st += hc*x;
  }
  float* o = ps + ((size_t)((b*NN+n)*2 + hh))*8;
  o[0]=s1; o[1]=s2; o[2]=s3; o[3]=s4; o[4]=st;
}

__global__ __launch_bounds__(256) void k_sumc(const float* __restrict__ ps, float* __restrict__ nf){
  int idx = blockIdx.x*256 + threadIdx.x;
  const float* a = ps + (size_t)idx*16;
  const float* c2 = a + 8;
  float s1 = a[0]+c2[0], s2 = a[1]+c2[1], s3 = a[2]+c2[2], s4 = a[3]+c2[3], st = a[4]+c2[4];
  float s1h = c2[0], s2h = c2[1];
  const float iH = 1.0f/168.0f, iHh = 1.0f/84.0f;
  float mean = s1*iH, meanh = s1h*iHh;
  float ex2 = s2*iH, ex3 = s3*iH, ex4 = s4*iH;
  float m2 = ex2 - mean*mean;
  float m3 = ex3 - 3.0f*mean*ex2 + 2.0f*mean*mean*mean;
  float m4 = ex4 - 4.0f*mean*ex3 + 6.0f*mean*mean*ex2 - 3.0f*mean*mean*mean*mean;
  m2 = fmaxf(m2, 0.0f);
  float stdf = sqrtf(m2);
  float m2h = fmaxf(s2h*iHh - meanh*meanh, 0.0f);
  float stdh = sqrtf(m2h);
  float denom = m2*stdf;
  float skew = denom > 0.0f ? m3/denom : 0.0f;
  float kurt = m2 > 0.0f ? (m4/(m2*m2) - 3.0f) : 0.0f;
  float slope = st * (1.0f/395122.0f);
  float* o = nf + (size_t)idx*7;
  o[0]=mean; o[1]=meanh; o[2]=stdf; o[3]=stdh; o[4]=skew; o[5]=kurt; o[6]=slope;
}

// ---------------- GCN layer 1 ----------------
__global__ __launch_bounds__(256) void k_gcn1(const float* __restrict__ nf, const float* __restrict__ adj,
        const float* __restrict__ w1, const float* __restrict__ b1, float* __restrict__ h1){
  __shared__ float t_s[NN*32];
  __shared__ float adj_s[128*68];
  int b = blockIdx.x>>2, n0 = (blockIdx.x&3)*128;
  int tid = threadIdx.x;
  {
    int c = tid&31;
    float w1c[7];
    #pragma unroll
    for(int k=0;k<7;++k) w1c[k] = w1[k*32+c];
    for(int idx=tid; idx<NN*32; idx+=256){
      int m = idx>>5;
      const float* nfp = nf + (size_t)(b*NN+m)*7;
      float acc = 0.f;
      #pragma unroll
      for(int k=0;k<7;++k) acc += nfp[k]*w1c[k];
      t_s[idx] = acc;
    }
  }
  int c2 = tid&15, nl = tid>>4;
  float acc[8][2];
  #pragma unroll
  for(int j=0;j<8;++j){acc[j][0]=0.f;acc[j][1]=0.f;}
  for(int mt=0; mt<8; ++mt){
    __syncthreads();
    for(int idx=tid; idx<128*64; idx+=256){
      int r = idx>>6, cc = idx&63;
      adj_s[r*68+cc] = adj[(size_t)(n0+r)*NN + mt*64 + cc];
    }
    __syncthreads();
    for(int mm=0; mm<64; mm+=4){
      float2 tv[4];
      #pragma unroll
      for(int q=0;q<4;++q) tv[q] = *(const float2*)&t_s[(mt*64+mm+q)*32 + 2*c2];
      #pragma unroll
      for(int j=0;j<8;++j){
        float4 a4 = *(const float4*)&adj_s[(nl+16*j)*68 + mm];
        acc[j][0] += a4.x*tv[0].x + a4.y*tv[1].x + a4.z*tv[2].x + a4.w*tv[3].x;
        acc[j][1] += a4.x*tv[0].y + a4.y*tv[1].y + a4.z*tv[2].y + a4.w*tv[3].y;
      }
    }
  }
  float bb0 = b1[2*c2], bb1 = b1[2*c2+1];
  #pragma unroll
  for(int j=0;j<8;++j){
    int n = n0 + nl + 16*j;
    float2 v;
    v.x = fmaxf(acc[j][0]+bb0, 0.0f);
    v.y = fmaxf(acc[j][1]+bb1, 0.0f);
    *(float2*)&h1[(size_t)(b*NN+n)*32 + 2*c2] = v;
  }
}

// ---------------- GCN layer 2 ----------------
__global__ __launch_bounds__(256) void k_gcn2(const float* __restrict__ h1, const float* __restrict__ adj,
        const float* __restrict__ w2, const float* __restrict__ b2, float* __restrict__ g){
  __shared__ float t_s[NN*16];
  __shared__ float adj_s[128*68];
  int b = blockIdx.x>>2, n0 = (blockIdx.x&3)*128;
  int tid = threadIdx.x;
  {
    int jh = tid&7;
    float w2c0[32], w2c1[32];
    #pragma unroll
    for(int c=0;c<32;++c){ w2c0[c] = w2[c*16+2*jh]; w2c1[c] = w2[c*16+2*jh+1]; }
    for(int idx=tid; idx<NN*8; idx+=256){
      int m = idx>>3;
      const float4* hp = (const float4*)(h1 + (size_t)(b*NN+m)*32);
      float a0=0.f, a1=0.f;
      #pragma unroll
      for(int q=0;q<8;++q){
        float4 hv = hp[q];
        a0 += hv.x*w2c0[4*q] + hv.y*w2c0[4*q+1] + hv.z*w2c0[4*q+2] + hv.w*w2c0[4*q+3];
        a1 += hv.x*w2c1[4*q] + hv.y*w2c1[4*q+1] + hv.z*w2c1[4*q+2] + hv.w*w2c1[4*q+3];
      }
      t_s[m*16+2*jh] = a0;
      t_s[m*16+2*jh+1] = a1;
    }
  }
  int j = tid&15, nl = tid>>4;
  float acc[8];
  #pragma unroll
  for(int q=0;q<8;++q) acc[q]=0.f;
  for(int mt=0; mt<8; ++mt){
    __syncthreads();
    for(int idx=tid; idx<128*64; idx+=256){
      int r = idx>>6, cc = idx&63;
      adj_s[r*68+cc] = adj[(size_t)(n0+r)*NN + mt*64 + cc];
    }
    __syncthreads();
    for(int mm=0; mm<64; mm+=4){
      float tv[4];
      #pragma unroll
      for(int q=0;q<4;++q) tv[q] = t_s[(mt*64+mm+q)*16 + j];
      #pragma unroll
      for(int q=0;q<8;++q){
        float4 a4 = *(const float4*)&adj_s[(nl+16*q)*68 + mm];
        acc[q] += a4.x*tv[0] + a4.y*tv[1] + a4.z*tv[2] + a4.w*tv[3];
      }
    }
  }
  float bbj = b2[j];
  #pragma unroll
  for(int q=0;q<8;++q){
    int n = n0 + nl + 16*q;
    g[(size_t)(b*NN+n)*16 + j] = fmaxf(acc[q]+bbj, 0.0f);
  }
}

// ---------------- conv1 -> pool -> conv2 ----------------
__global__ __launch_bounds__(256) void k_conv(const float* __restrict__ g, const float* __restrict__ wc1,
        const float* __restrict__ bc1, const float* __restrict__ wc2, const float* __restrict__ bc2,
        float* __restrict__ feat){
  __shared__ float g_s[NN*16];
  __shared__ float w1_s[3*NN*4];
  __shared__ float c1p[4][4][16];
  __shared__ float c1_s[4][16];
  __shared__ float p_s[4][8];
  int b = blockIdx.x, tid = threadIdx.x;
  for(int idx=tid; idx<NN*16; idx+=256) g_s[idx] = g[(size_t)b*NN*16 + idx];
  for(int idx=tid; idx<3*NN*4; idx+=256) w1_s[idx] = wc1[idx];
  __syncthreads();
  {
    int q = tid>>6, p = tid&63, o = p>>4, x = p&15;
    int c0 = q*128;
    float acc = 0.f;
    #pragma unroll
    for(int k=0;k<3;++k){
      int xx = x + k - 1;
      if(xx>=0 && xx<16){
        #pragma unroll 4
        for(int c=c0;c<c0+128;++c) acc += g_s[c*16+xx]*w1_s[(k*NN+c)*4+o];
      }
    }
    c1p[q][o][x] = acc;
  }
  __syncthreads();
  if(tid<64){
    int o = tid>>4, x = tid&15;
    c1_s[o][x] = c1p[0][o][x]+c1p[1][o][x]+c1p[2][o][x]+c1p[3][o][x] + bc1[o];
  }
  __syncthreads();
  if(tid<32){
    int oo = tid>>3, xp = tid&7;
    float pv = 0.5f*(c1_s[oo][2*xp]+c1_s[oo][2*xp+1]);
    p_s[oo][xp] = pv;
    feat[b*192 + 32 + oo*8 + xp] = pv;
  }
  __syncthreads();
  if(tid<32){
    int oo = tid>>3, x2 = tid&7;
    float a2 = bc2[oo];
    #pragma unroll
    for(int k=0;k<3;++k){
      int xx = x2 + k - 1;
      if(xx>=0 && xx<8){
        #pragma unroll
        for(int c=0;c<4;++c) a2 += p_s[c][xx]*wc2[(k*4+c)*4+oo];
      }
    }
    feat[b*192 + oo*8 + x2] = a2;
  }
}

// ---------------- LSTM1: 512 threads, quad split-k, shuffle reduce ----------------
// thread t: q=t&3 (h slice q*32..q*32+31), g=t>>2 (cols 4g..4g+3); reduced z lands at col t.
__global__ __launch_bounds__(512,2) void k_lstm1(const float* __restrict__ in, const float* __restrict__ k1,
        const float* __restrict__ rk1, const float* __restrict__ b1, float* __restrict__ l1){
  __shared__ float seq_s[HH*FF];      // 5.25KB
  __shared__ float h_s2[4*36];        // stride-36 rows: slice q at h_s2[q*36+k]
  __shared__ float a_s[GD];           // 2KB activations
  int b = blockIdx.x, tid = threadIdx.x;
  int q = tid&3, grp = tid>>2;
  bool q0 = (tid&1)!=0, q1 = (tid&2)!=0;
  // weights: w4[k] = rk[(q*32+k)][4g..4g+3]
  float4 w4[32];
  {
    const float4* rkp = (const float4*)rk1;
    #pragma unroll
    for(int k=0;k<32;++k) w4[k] = rkp[(size_t)(q*32+k)*(GD/4) + grp];
  }
  float wkx[FF];
  #pragma unroll
  for(int f=0;f<FF;++f) wkx[f] = k1[f*GD+tid];
  float bz = b1[tid];
  for(int idx=tid; idx<HH*FF; idx+=512)
    seq_s[idx] = in[(size_t)(b*HH + (idx>>3))*NN*FF + (idx&7)];
  if(tid<UL) h_s2[(tid>>5)*36 + (tid&31)] = 0.0f;
  float c = 0.0f;
  __syncthreads();
  const float4* hq = (const float4*)&h_s2[q*36];
  #pragma unroll 1
  for(int t=0;t<HH;++t){
    // x-projection (broadcast reads)
    float4 x0 = *(const float4*)&seq_s[t*FF];
    float4 x1 = *(const float4*)&seq_s[t*FF+4];
    float zx = bz + x0.x*wkx[0]+x0.y*wkx[1]+x0.z*wkx[2]+x0.w*wkx[3]
                  + x1.x*wkx[4]+x1.y*wkx[5]+x1.z*wkx[6]+x1.w*wkx[7];
    // partial dots over h slice q
    float p0=0.f,p1=0.f,p2=0.f,p3=0.f;
    #pragma unroll
    for(int j=0;j<8;++j){
      float4 hv = hq[j];
      p0 += hv.x*w4[4*j].x + hv.y*w4[4*j+1].x + hv.z*w4[4*j+2].x + hv.w*w4[4*j+3].x;
      p1 += hv.x*w4[4*j].y + hv.y*w4[4*j+1].y + hv.z*w4[4*j+2].y + hv.w*w4[4*j+3].y;
      p2 += hv.x*w4[4*j].z + hv.y*w4[4*j+1].z + hv.z*w4[4*j+2].z + hv.w*w4[4*j+3].z;
      p3 += hv.x*w4[4*j].w + hv.y*w4[4*j+1].w + hv.z*w4[4*j+2].w + hv.w*w4[4*j+3].w;
    }
    // quad transpose-reduce: thread ends with col = tid
    float send0 = q0 ? p0 : p1;
    float send1 = q0 ? p2 : p3;
    float r0 = __shfl_xor(send0, 1);
    float r1 = __shfl_xor(send1, 1);
    float s0 = (q0 ? p1 : p0) + r0;
    float s1 = (q0 ? p3 : p2) + r1;
    float send2 = q1 ? s0 : s1;
    float r2 = __shfl_xor(send2, 2);
    float z = zx + (q1 ? s1 : s0) + r2;
    // activation: gate = tid>>7 (wave-uniform)
    float act = ((tid>>7)==2) ? tanhfast(z) : sigf(z);
    a_s[tid] = act;
    __syncthreads();
    // cell update (all threads redundantly for u=tid&127; writers: tid<128)
    int u = tid&127;
    float ia=a_s[u], fa=a_s[UL+u], ga=a_s[2*UL+u], oa=a_s[3*UL+u];
    c = fa*c + ia*ga;
    float hn = oa*tanhfast(c);
    if(tid<UL){
      h_s2[(tid>>5)*36 + (tid&31)] = hn;
      l1[((size_t)b*HH + t)*UL + tid] = hn;
    }
    __syncthreads();
  }
}

// ---------------- zin2 = l1 @ k2 + b2 ----------------
__global__ __launch_bounds__(256) void k_zin2(const float* __restrict__ l1, const float* __restrict__ k2,
        const float* __restrict__ b2, float* __restrict__ zin){
  __shared__ float l_s[21*UL];
  int b = blockIdx.x>>3, t0 = (blockIdx.x&7)*21;
  int tid = threadIdx.x;
  for(int idx=tid; idx<21*UL; idx+=256)
    l_s[idx] = l1[((size_t)b*HH + t0 + (idx>>7))*UL + (idx&127)];
  __syncthreads();
  float acc0[21], acc1[21];
  #pragma unroll
  for(int q=0;q<21;++q){acc0[q]=0.f;acc1[q]=0.f;}
  for(int j=0;j<UL;j+=4){
    float kv00=k2[j*GD+tid],     kv01=k2[(j+1)*GD+tid],     kv02=k2[(j+2)*GD+tid],     kv03=k2[(j+3)*GD+tid];
    float kv10=k2[j*GD+tid+256], kv11=k2[(j+1)*GD+tid+256], kv12=k2[(j+2)*GD+tid+256], kv13=k2[(j+3)*GD+tid+256];
    #pragma unroll
    for(int q=0;q<21;++q){
      float4 lv = *(const float4*)&l_s[q*UL + j];
      acc0[q] += lv.x*kv00 + lv.y*kv01 + lv.z*kv02 + lv.w*kv03;
      acc1[q] += lv.x*kv10 + lv.y*kv11 + lv.z*kv12 + lv.w*kv13;
    }
  }
  float bb0 = b2[tid], bb1 = b2[tid+256];
  #pragma unroll
  for(int q=0;q<21;++q){
    zin[((size_t)b*HH + t0 + q)*GD + tid]       = acc0[q] + bb0;
    zin[((size_t)b*HH + t0 + q)*GD + tid + 256] = acc1[q] + bb1;
  }
}

// ---------------- LSTM2: same structure, z from precomputed zin ----------------
__global__ __launch_bounds__(512,2) void k_lstm2(const float* __restrict__ zin, const float* __restrict__ rk2,
        float* __restrict__ feat){
  __shared__ float h_s2[4*36];
  __shared__ float a_s[GD];
  int b = blockIdx.x, tid = threadIdx.x;
  int q = tid&3, grp = tid>>2;
  bool q0 = (tid&1)!=0, q1 = (tid&2)!=0;
  float4 w4[32];
  {
    const float4* rkp = (const float4*)rk2;
    #pragma unroll
    for(int k=0;k<32;++k) w4[k] = rkp[(size_t)(q*32+k)*(GD/4) + grp];
  }
  if(tid<UL) h_s2[(tid>>5)*36 + (tid&31)] = 0.0f;
  float c = 0.0f;
  float zc = zin[((size_t)b*HH)*GD + tid];
  __syncthreads();
  const float4* hq = (const float4*)&h_s2[q*36];
  #pragma unroll 1
  for(int t=0;t<HH;++t){
    float nz = 0.f;
    if(t+1<HH) nz = zin[((size_t)b*HH+t+1)*GD + tid];
    float p0=0.f,p1=0.f,p2=0.f,p3=0.f;
    #pragma unroll
    for(int j=0;j<8;++j){
      float4 hv = hq[j];
      p0 += hv.x*w4[4*j].x + hv.y*w4[4*j+1].x + hv.z*w4[4*j+2].x + hv.w*w4[4*j+3].x;
      p1 += hv.x*w4[4*j].y + hv.y*w4[4*j+1].y + hv.z*w4[4*j+2].y + hv.w*w4[4*j+3].y;
      p2 += hv.x*w4[4*j].z + hv.y*w4[4*j+1].z + hv.z*w4[4*j+2].z + hv.w*w4[4*j+3].z;
      p3 += hv.x*w4[4*j].w + hv.y*w4[4*j+1].w + hv.z*w4[4*j+2].w + hv.w*w4[4*j+3].w;
    }
    float send0 = q0 ? p0 : p1;
    float send1 = q0 ? p2 : p3;
    float r0 = __shfl_xor(send0, 1);
    float r1 = __shfl_xor(send1, 1);
    float s0 = (q0 ? p1 : p0) + r0;
    float s1 = (q0 ? p3 : p2) + r1;
    float send2 = q1 ? s0 : s1;
    float r2 = __shfl_xor(send2, 2);
    float z = zc + (q1 ? s1 : s0) + r2;
    float act = ((tid>>7)==2) ? tanhfast(z) : sigf(z);
    a_s[tid] = act;
    __syncthreads();
    int u = tid&127;
    float ia=a_s[u], fa=a_s[UL+u], ga=a_s[2*UL+u], oa=a_s[3*UL+u];
    c = fa*c + ia*ga;
    float hn = oa*tanhfast(c);
    if(tid<UL){
      h_s2[(tid>>5)*36 + (tid&31)] = hn;
      if(t==HH-1) feat[b*192 + 64 + tid] = hn;
    }
    __syncthreads();
    zc = nz;
  }
}

// ---------------- final dense ----------------
__global__ __launch_bounds__(256) void k_out(const float* __restrict__ feat, const float* __restrict__ wo,
        const float* __restrict__ bo, float* __restrict__ out){
  int idx = blockIdx.x*256 + threadIdx.x;
  if(idx >= BB*24) return;
  int b = idx/24, p = idx - b*24;
  float a0 = bo[p], a1 = 0.f, a2 = 0.f, a3 = 0.f;
  const float* f = feat + b*192;
  for(int k=0;k<192;k+=4){
    a0 += f[k]*wo[k*24+p];
    a1 += f[k+1]*wo[(k+1)*24+p];
    a2 += f[k+2]*wo[(k+2)*24+p];
    a3 += f[k+3]*wo[(k+3)*24+p];
  }
  out[idx] = (a0+a1)+(a2+a3);
}

extern "C" void kernel_launch(void* const* d_in, const int* in_sizes, int n_in,
                              void* d_out, int out_size, void* d_ws, size_t ws_size,
                              hipStream_t stream){
  const float* inp = (const float*)d_in[0];
  const float* adj = (const float*)d_in[1];
  const float* w1  = (const float*)d_in[2];
  const float* b1  = (const float*)d_in[3];
  const float* w2  = (const float*)d_in[4];
  const float* b2  = (const float*)d_in[5];
  const float* wc1 = (const float*)d_in[6];
  const float* bc1 = (const float*)d_in[7];
  const float* wc2 = (const float*)d_in[8];
  const float* bc2 = (const float*)d_in[9];
  const float* k1  = (const float*)d_in[10];
  const float* rk1 = (const float*)d_in[11];
  const float* bl1 = (const float*)d_in[12];
  const float* k2  = (const float*)d_in[13];
  const float* rk2 = (const float*)d_in[14];
  const float* bl2 = (const float*)d_in[15];
  const float* wo  = (const float*)d_in[16];
  const float* bo  = (const float*)d_in[17];
  float* out = (float*)d_out;
  float* ws = (float*)d_ws;

  float* ps   = ws;
  float* nf   = ps + 524288;
  float* h1   = nf + 229376;
  float* g    = h1 + 1048576;
  float* feat = g  + 524288;
  float* l1   = feat + 12288;
  float* zin  = l1 + 1376256;

  k_sum  <<<dim3(256), dim3(256), 0, stream>>>(inp, ps);
  k_sumc <<<dim3(128), dim3(256), 0, stream>>>(ps, nf);
  k_gcn1 <<<dim3(256), dim3(256), 0, stream>>>(nf, adj, w1, b1, h1);
  k_gcn2 <<<dim3(256), dim3(256), 0, stream>>>(h1, adj, w2, b2, g);
  k_conv <<<dim3(64),  dim3(256), 0, stream>>>(g, wc1, bc1, wc2, bc2, feat);
  k_lstm1<<<dim3(64),  dim3(512), 0, stream>>>(inp, k1, rk1, bl1, l1);
  k_zin2 <<<dim3(512), dim3(256), 0, stream>>>(l1, k2, bl2, zin);
  k_lstm2<<<dim3(64),  dim3(512), 0, stream>>>(zin, rk2, feat);
  k_out  <<<dim3(6),   dim3(256), 0, stream>>>(feat, wo, bo, out);
}